// Round 2
// baseline (1247.264 us; speedup 1.0000x reference)
//
#include <hip/hip_runtime.h>
#include <stdint.h>

typedef unsigned short u16;
typedef u16    u16x8  __attribute__((ext_vector_type(8)));
typedef __bf16 bf16x8 __attribute__((ext_vector_type(8)));
typedef float  f32x4  __attribute__((ext_vector_type(4)));

#define TOKS 50176   // B*H*W = 16*56*56
#define CD   512

__device__ __forceinline__ float bf2f(u16 u) {
    union { unsigned int i; float f; } c; c.i = ((unsigned int)u) << 16; return c.f;
}
__device__ __forceinline__ u16 f2bf(float f) {
    union { float f; unsigned int i; } c; c.f = f;
    unsigned int x = c.i;
    return (u16)((x + 0x7fffu + ((x >> 16) & 1u)) >> 16);
}
__device__ __forceinline__ float gelu_tanh(float x) {
    float t = 0.7978845608028654f * (x + 0.044715f * x * x * x);
    float e = __expf(2.0f * t);
    float th = 1.0f - 2.0f / (e + 1.0f);
    return 0.5f * x * (1.0f + th);
}

// global -> LDS direct (16B per lane, wave-uniform LDS base + lane*16)
typedef const __attribute__((address_space(1))) unsigned int gas_u32;
typedef __attribute__((address_space(3))) unsigned int las_u32;
__device__ __forceinline__ void gload16(const u16* g, u16* l) {
    __builtin_amdgcn_global_load_lds((gas_u32*)g, (las_u32*)l, 16, 0, 0);
}

// ---------------- weight transpose + cast: src[K][N] f32 -> dst[N][K] bf16 ----
__global__ __launch_bounds__(256)
void k_transpose_cast(const float* __restrict__ src, u16* __restrict__ dst,
                      const int K, const int N)
{
    __shared__ float tile[32][33];
    const int tx = threadIdx.x & 31, ty = threadIdx.x >> 5;  // ty 0..7
    const int n0 = blockIdx.x * 32, k0 = blockIdx.y * 32;
    #pragma unroll
    for (int i = 0; i < 4; ++i) {
        int r = ty + i * 8;
        tile[r][tx] = src[(size_t)(k0 + r) * N + n0 + tx];
    }
    __syncthreads();
    #pragma unroll
    for (int i = 0; i < 4; ++i) {
        int r = ty + i * 8;
        dst[(size_t)(n0 + r) * K + k0 + tx] = f2bf(tile[tx][r]);
    }
}

// ---------------- LayerNorm over C=512, f32 in -> bf16 out ------------------
__global__ __launch_bounds__(256)
void k_layernorm(const float* __restrict__ x, const float* __restrict__ g,
                 const float* __restrict__ bvec, u16* __restrict__ out)
{
    const int l = threadIdx.x & 63;
    const int w = threadIdx.x >> 6;
    const size_t row = (size_t)blockIdx.x * 4 + w;
    const float* xr = x + row * CD + l * 8;
    f32x4 v0 = *(const f32x4*)xr;
    f32x4 v1 = *(const f32x4*)(xr + 4);
    float s = 0.f, sq = 0.f;
    #pragma unroll
    for (int i = 0; i < 4; ++i) { s += v0[i]; sq += v0[i] * v0[i]; }
    #pragma unroll
    for (int i = 0; i < 4; ++i) { s += v1[i]; sq += v1[i] * v1[i]; }
    #pragma unroll
    for (int off = 32; off > 0; off >>= 1) {
        s  += __shfl_xor(s, off);
        sq += __shfl_xor(sq, off);
    }
    const float mean = s * (1.0f / 512.0f);
    const float var  = fmaxf(sq * (1.0f / 512.0f) - mean * mean, 0.0f);
    const float rstd = rsqrtf(var + 1e-6f);
    const int c = l * 8;
    f32x4 g0 = *(const f32x4*)(g + c),    g1 = *(const f32x4*)(g + c + 4);
    f32x4 b0 = *(const f32x4*)(bvec + c), b1 = *(const f32x4*)(bvec + c + 4);
    u16x8 o;
    #pragma unroll
    for (int i = 0; i < 4; ++i) o[i]     = f2bf((v0[i] - mean) * rstd * g0[i] + b0[i]);
    #pragma unroll
    for (int i = 0; i < 4; ++i) o[4 + i] = f2bf((v1[i] - mean) * rstd * g1[i] + b1[i]);
    *(u16x8*)(out + row * CD + c) = o;
}

// ---------------- bf16 GEMM: C[M][N] = A[M][K] @ Bt[N][K]^T + bias ----------
// EPI: 0 = bias -> bf16 ; 1 = bias+gelu -> bf16 ; 2 = bias + f32 residual -> f32
// 128x128 tile, 4 waves (2x2), BK=32, mfma_f32_16x16x32_bf16.
// Staging via global_load_lds (16B/lane); LDS slots XOR-swizzled (16B slot
// index p = lam ^ ((lam>>3)&7)) so ds_read_b128 is bank-conflict-free; the
// swizzle is applied by permuting the per-lane GLOBAL source address (linear
// LDS dest, rule: both-sides-or-neither).
// Grid: blockIdx.x = n-block (fast), blockIdx.y = m-block -> A-panel reuse in L2.
template<int EPI>
__global__ __launch_bounds__(256)
void k_gemm(const u16* __restrict__ A, const u16* __restrict__ Bt,
            const float* __restrict__ bias, const float* __restrict__ resid,
            u16* __restrict__ outb, float* __restrict__ outf,
            const int N, const int K)
{
    __shared__ u16 As[128 * 32];
    __shared__ u16 Bs[128 * 32];
    const int t  = threadIdx.x;
    const int l  = t & 63;
    const int w  = t >> 6;
    const int wr = w >> 1, wc = w & 1;          // 2x2 wave grid, each wave 64x64
    const int m0 = blockIdx.y * 128, n0 = blockIdx.x * 128;
    const int kq = l >> 4;                      // frag k-slot 0..3
    const int fr = l & 15;                      // frag row/col

    // staging: thread t fills physical 16B slot t (and t+256); source element
    // is logical slot lam = t ^ ((t>>3)&7)  (involution; bits>=3 unchanged)
    const int lam  = t ^ ((t >> 3) & 7);
    const int srow = lam >> 2;                  // 0..63
    const int skq  = lam & 3;
    const u16* Asrc0 = A  + (size_t)(m0 + srow) * K      + skq * 8;
    const u16* Asrc1 = A  + (size_t)(m0 + 64 + srow) * K + skq * 8;
    const u16* Bsrc0 = Bt + (size_t)(n0 + srow) * K      + skq * 8;
    const u16* Bsrc1 = Bt + (size_t)(n0 + 64 + srow) * K + skq * 8;
    u16* Adst0 = As + w * 512;                  // wave-uniform base, +lane*16B by HW
    u16* Adst1 = As + 2048 + w * 512;
    u16* Bdst0 = Bs + w * 512;
    u16* Bdst1 = Bs + 2048 + w * 512;

    // swizzled read offsets (u16 units), loop-invariant
    int offA[4], offB[4];
    #pragma unroll
    for (int mi = 0; mi < 4; ++mi) {
        int lr = (wr * 64 + mi * 16 + fr) * 4 + kq;
        offA[mi] = (lr ^ ((lr >> 3) & 7)) * 8;
    }
    #pragma unroll
    for (int ni = 0; ni < 4; ++ni) {
        int lr = (wc * 64 + ni * 16 + fr) * 4 + kq;
        offB[ni] = (lr ^ ((lr >> 3) & 7)) * 8;
    }

    f32x4 acc[4][4];
    #pragma unroll
    for (int i = 0; i < 4; ++i)
        #pragma unroll
        for (int j = 0; j < 4; ++j) {
            f32x4 z = {0.f, 0.f, 0.f, 0.f};
            acc[i][j] = z;
        }

    for (int k0 = 0; k0 < K; k0 += 32) {
        __syncthreads();                 // prior reads done before overwrite
        gload16(Asrc0 + k0, Adst0);
        gload16(Asrc1 + k0, Adst1);
        gload16(Bsrc0 + k0, Bdst0);
        gload16(Bsrc1 + k0, Bdst1);
        asm volatile("s_waitcnt vmcnt(0)" ::: "memory");
        __syncthreads();
        bf16x8 af[4], bfv[4];
        #pragma unroll
        for (int mi = 0; mi < 4; ++mi) af[mi]  = *(const bf16x8*)&As[offA[mi]];
        #pragma unroll
        for (int ni = 0; ni < 4; ++ni) bfv[ni] = *(const bf16x8*)&Bs[offB[ni]];
        #pragma unroll
        for (int mi = 0; mi < 4; ++mi)
            #pragma unroll
            for (int ni = 0; ni < 4; ++ni)
                acc[mi][ni] = __builtin_amdgcn_mfma_f32_16x16x32_bf16(
                    af[mi], bfv[ni], acc[mi][ni], 0, 0, 0);
    }

    float bv[4];
    #pragma unroll
    for (int ni = 0; ni < 4; ++ni) bv[ni] = bias[n0 + wc * 64 + ni * 16 + fr];

    #pragma unroll
    for (int mi = 0; mi < 4; ++mi) {
        #pragma unroll
        for (int r = 0; r < 4; ++r) {
            const size_t row  = (size_t)(m0 + wr * 64 + mi * 16 + kq * 4 + r);
            const size_t base = row * N + n0 + wc * 64 + fr;
            #pragma unroll
            for (int ni = 0; ni < 4; ++ni) {
                float v = acc[mi][ni][r] + bv[ni];
                if (EPI == 1) v = gelu_tanh(v);
                if (EPI == 2) outf[base + ni * 16] = v + resid[base + ni * 16];
                else          outb[base + ni * 16] = f2bf(v);
            }
        }
    }
}

// ---------------- windowed attention: 1 wave per (window, head) -------------
__global__ __launch_bounds__(64)
void k_attn(const u16* __restrict__ qkv, const float* __restrict__ btab,
            u16* __restrict__ o, const int tok_base)
{
    __shared__ float Ss[64 * 53];
    const int l    = threadIdx.x;
    const int widl = blockIdx.x >> 4;       // window within chunk (0..127)
    const int head = blockIdx.x & 15;
    const int bl   = widl >> 6;
    const int g    = widl & 63;
    const int gh   = g >> 3, gw = g & 7;
    const int tok00 = bl * 3136 + gh * 392 + gw * 7;
    const int pl = (l < 49) ? l : 48;
    const int ph = pl / 7, pw = pl - (pl / 7) * 7;
    const int tokl = tok00 + ph * 56 + pw;

    float q[32];
    {
        const size_t qoff = (size_t)tokl * 1536 + head * 32;
        #pragma unroll
        for (int i = 0; i < 4; ++i) {
            u16x8 u = *(const u16x8*)(qkv + qoff + i * 8);
            #pragma unroll
            for (int j = 0; j < 8; ++j) q[i * 8 + j] = bf2f(u[j]);
        }
    }

    float rowmax = -1e30f;
    {
        int j = 0;
        for (int jh = 0; jh < 7; ++jh) {
            for (int jw = 0; jw < 7; ++jw, ++j) {
                const size_t koff = (size_t)(tok00 + jh * 56 + jw) * 1536 + 512 + head * 32;
                float d0 = 0.f, d1 = 0.f, d2 = 0.f, d3 = 0.f;
                #pragma unroll
                for (int i = 0; i < 4; ++i) {
                    u16x8 u = *(const u16x8*)(qkv + koff + i * 8);
                    d0 += q[i * 8 + 0] * bf2f(u[0]); d0 += q[i * 8 + 1] * bf2f(u[1]);
                    d1 += q[i * 8 + 2] * bf2f(u[2]); d1 += q[i * 8 + 3] * bf2f(u[3]);
                    d2 += q[i * 8 + 4] * bf2f(u[4]); d2 += q[i * 8 + 5] * bf2f(u[5]);
                    d3 += q[i * 8 + 6] * bf2f(u[6]); d3 += q[i * 8 + 7] * bf2f(u[7]);
                }
                const float bias = btab[(size_t)((ph - jh + 6) * 13 + (pw - jw + 6)) * 16 + head];
                const float sc = (d0 + d1 + d2 + d3) * 0.04419417382415922f + bias;
                rowmax = fmaxf(rowmax, sc);
                Ss[l * 53 + j] = sc;
            }
        }
    }

    float sum = 0.f;
    for (int j = 0; j < 49; ++j) {
        float p = __expf(Ss[l * 53 + j] - rowmax);
        sum += p;
        Ss[l * 53 + j] = p;
    }

    float oa[32];
    #pragma unroll
    for (int i = 0; i < 32; ++i) oa[i] = 0.f;
    {
        int j = 0;
        for (int jh = 0; jh < 7; ++jh) {
            for (int jw = 0; jw < 7; ++jw, ++j) {
                const size_t voff = (size_t)(tok00 + jh * 56 + jw) * 1536 + 1024 + head * 32;
                const float p = Ss[l * 53 + j];
                #pragma unroll
                for (int i = 0; i < 4; ++i) {
                    u16x8 u = *(const u16x8*)(qkv + voff + i * 8);
                    #pragma unroll
                    for (int jj = 0; jj < 8; ++jj) oa[i * 8 + jj] += p * bf2f(u[jj]);
                }
            }
        }
    }

    if (l < 49) {
        const float inv = 1.0f / sum;
        const size_t obase = (size_t)(tok_base + tokl) * CD + head * 32;
        #pragma unroll
        for (int i = 0; i < 4; ++i) {
            u16x8 u;
            #pragma unroll
            for (int jj = 0; jj < 8; ++jj) u[jj] = f2bf(oa[i * 8 + jj] * inv);
            *(u16x8*)(o + obase + i * 8) = u;
        }
    }
}

// ---------------------------------------------------------------------------
extern "C" void kernel_launch(void* const* d_in, const int* in_sizes, int n_in,
                              void* d_out, int out_size, void* d_ws, size_t ws_size,
                              hipStream_t stream)
{
    (void)in_sizes; (void)n_in; (void)out_size; (void)ws_size;
    const float* x     = (const float*)d_in[0];
    const float* ln1_s = (const float*)d_in[1];
    const float* ln1_b = (const float*)d_in[2];
    const float* w_qkv = (const float*)d_in[3];
    const float* b_qkv = (const float*)d_in[4];
    const float* btab  = (const float*)d_in[5];
    const float* w_mrg = (const float*)d_in[6];
    const float* b_mrg = (const float*)d_in[7];
    const float* ln2_s = (const float*)d_in[8];
    const float* ln2_b = (const float*)d_in[9];
    const float* w1    = (const float*)d_in[10];
    const float* b1    = (const float*)d_in[11];
    const float* w2    = (const float*)d_in[12];
    const float* b2    = (const float*)d_in[13];
    float* out = (float*)d_out;

    // ---- workspace layout (total ~318.4 MiB) ----
    u16* wqkvT = (u16*)d_ws;                                // [1536][512]
    u16* wmrgT = wqkvT + (size_t)1536 * 512;                // [512][512]
    u16* w1T   = wmrgT + (size_t)512 * 512;                 // [2048][512]
    u16* w2T   = w1T   + (size_t)2048 * 512;                // [512][2048]
    u16* hbuf  = w2T   + (size_t)512 * 2048;                // [TOKS][512] h, then o
    u16* mbuf  = hbuf  + (size_t)TOKS * 512;                // [TOKS][512] LN2 out
    float* y1  = (float*)(mbuf + (size_t)TOKS * 512);       // [TOKS][512] f32 residual
    u16* qkvc  = (u16*)(y1 + (size_t)TOKS * 512);           // [6272][1536] chunk
    u16* hidc  = qkvc + (size_t)6272 * 1536;                // [25088][2048] chunk

    dim3 B256(256);

    // weights: transpose + cast to bf16 [N][K]
    k_transpose_cast<<<dim3(48, 16), B256, 0, stream>>>(w_qkv, wqkvT, 512, 1536);
    k_transpose_cast<<<dim3(16, 16), B256, 0, stream>>>(w_mrg, wmrgT, 512, 512);
    k_transpose_cast<<<dim3(64, 16), B256, 0, stream>>>(w1,   w1T,   512, 2048);
    k_transpose_cast<<<dim3(16, 64), B256, 0, stream>>>(w2,   w2T,   2048, 512);

    // LN1: x -> h (bf16)
    k_layernorm<<<dim3(TOKS / 4), B256, 0, stream>>>(x, ln1_s, ln1_b, hbuf);

    // QKV GEMM + attention, chunked over 2 batches (6272 tokens = 49*128 rows)
    for (int c = 0; c < 8; ++c) {
        const size_t tb = (size_t)c * 6272;
        k_gemm<0><<<dim3(12, 49), B256, 0, stream>>>(
            hbuf + tb * 512, wqkvT, b_qkv, nullptr, qkvc, nullptr, 1536, 512);
        k_attn<<<dim3(128 * 16), dim3(64), 0, stream>>>(qkvc, btab, hbuf, (int)tb);
    }

    // merge GEMM + residual(x) -> y1 (f32)
    k_gemm<2><<<dim3(4, 392), B256, 0, stream>>>(
        hbuf, wmrgT, b_mrg, x, nullptr, y1, 512, 512);

    // LN2: y1 -> m (bf16)
    k_layernorm<<<dim3(TOKS / 4), B256, 0, stream>>>(y1, ln2_s, ln2_b, mbuf);

    // MLP, chunked over 25088 rows (=196*128)
    for (int c = 0; c < 2; ++c) {
        const size_t rb = (size_t)c * 25088;
        k_gemm<1><<<dim3(16, 196), B256, 0, stream>>>(
            mbuf + rb * 512, w1T, b1, nullptr, hidc, nullptr, 2048, 512);
        k_gemm<2><<<dim3(4, 196), B256, 0, stream>>>(
            hidc, w2T, b2, y1 + rb * 512, nullptr, out + rb * 512, 512, 2048);
    }
}

// Round 3
// 1241.803 us; speedup vs baseline: 1.0044x; 1.0044x over previous
//
#include <hip/hip_runtime.h>
#include <stdint.h>

typedef unsigned short u16;
typedef u16    u16x8  __attribute__((ext_vector_type(8)));
typedef __bf16 bf16x8 __attribute__((ext_vector_type(8)));
typedef float  f32x4  __attribute__((ext_vector_type(4)));

#define TOKS 50176   // B*H*W = 16*56*56
#define CD   512

__device__ __forceinline__ float bf2f(u16 u) {
    union { unsigned int i; float f; } c; c.i = ((unsigned int)u) << 16; return c.f;
}
__device__ __forceinline__ u16 f2bf(float f) {
    union { float f; unsigned int i; } c; c.f = f;
    unsigned int x = c.i;
    return (u16)((x + 0x7fffu + ((x >> 16) & 1u)) >> 16);
}
__device__ __forceinline__ float gelu_tanh(float x) {
    float t = 0.7978845608028654f * (x + 0.044715f * x * x * x);
    float e = __expf(2.0f * t);
    float th = 1.0f - 2.0f / (e + 1.0f);
    return 0.5f * x * (1.0f + th);
}

// global -> LDS direct (16B per lane, wave-uniform LDS base + lane*16)
typedef const __attribute__((address_space(1))) unsigned int gas_u32;
typedef __attribute__((address_space(3))) unsigned int las_u32;
__device__ __forceinline__ void gload16(const u16* g, u16* l) {
    __builtin_amdgcn_global_load_lds((gas_u32*)g, (las_u32*)l, 16, 0, 0);
}

// ---------------- weight transpose + cast: src[K][N] f32 -> dst[N][K] bf16 ----
__global__ __launch_bounds__(256)
void k_transpose_cast(const float* __restrict__ src, u16* __restrict__ dst,
                      const int K, const int N)
{
    __shared__ float tile[32][33];
    const int tx = threadIdx.x & 31, ty = threadIdx.x >> 5;  // ty 0..7
    const int n0 = blockIdx.x * 32, k0 = blockIdx.y * 32;
    #pragma unroll
    for (int i = 0; i < 4; ++i) {
        int r = ty + i * 8;
        tile[r][tx] = src[(size_t)(k0 + r) * N + n0 + tx];
    }
    __syncthreads();
    #pragma unroll
    for (int i = 0; i < 4; ++i) {
        int r = ty + i * 8;
        dst[(size_t)(n0 + r) * K + k0 + tx] = f2bf(tile[tx][r]);
    }
}

// ---------------- LayerNorm over C=512 -> bf16 out --------------------------
// BF=0: f32 input, BF=1: bf16 input
template<int BF>
__global__ __launch_bounds__(256)
void k_layernorm(const void* __restrict__ xin, const float* __restrict__ g,
                 const float* __restrict__ bvec, u16* __restrict__ out)
{
    const int l = threadIdx.x & 63;
    const int w = threadIdx.x >> 6;
    const size_t row = (size_t)blockIdx.x * 4 + w;
    const int c = l * 8;
    float v[8];
    if (BF) {
        u16x8 u = *(const u16x8*)((const u16*)xin + row * CD + c);
        #pragma unroll
        for (int i = 0; i < 8; ++i) v[i] = bf2f(u[i]);
    } else {
        f32x4 a0 = *(const f32x4*)((const float*)xin + row * CD + c);
        f32x4 a1 = *(const f32x4*)((const float*)xin + row * CD + c + 4);
        #pragma unroll
        for (int i = 0; i < 4; ++i) { v[i] = a0[i]; v[4 + i] = a1[i]; }
    }
    float s = 0.f, sq = 0.f;
    #pragma unroll
    for (int i = 0; i < 8; ++i) { s += v[i]; sq += v[i] * v[i]; }
    #pragma unroll
    for (int off = 32; off > 0; off >>= 1) {
        s  += __shfl_xor(s, off);
        sq += __shfl_xor(sq, off);
    }
    const float mean = s * (1.0f / 512.0f);
    const float var  = fmaxf(sq * (1.0f / 512.0f) - mean * mean, 0.0f);
    const float rstd = rsqrtf(var + 1e-6f);
    f32x4 g0 = *(const f32x4*)(g + c),    g1 = *(const f32x4*)(g + c + 4);
    f32x4 b0 = *(const f32x4*)(bvec + c), b1 = *(const f32x4*)(bvec + c + 4);
    u16x8 o;
    #pragma unroll
    for (int i = 0; i < 4; ++i) o[i]     = f2bf((v[i] - mean) * rstd * g0[i] + b0[i]);
    #pragma unroll
    for (int i = 0; i < 4; ++i) o[4 + i] = f2bf((v[4+i] - mean) * rstd * g1[i] + b1[i]);
    *(u16x8*)(out + row * CD + c) = o;
}

// ---------------- bf16 GEMM 256x256, BK=32, 8 waves, prefetch-pipelined -----
// C[M][N] = A[M][K] @ Bt[N][K]^T + bias, M % 256 == 0, N % 256 == 0, K % 32 == 0
// EPI: 0 = bias -> bf16
//      1 = bias + gelu -> bf16
//      2 = bias + f32 resid -> bf16
//      3 = bias + bf16 resid -> f32
// LDS double-buffered (64 KB). Staging: global_load_lds 16B/lane, linear LDS
// dest, source pre-swizzled (slot s ^= (row>>1)&3) so ds_read_b128 frag reads
// are bank-conflict-free. Per-iter: issue next-tile loads, compute current,
// drain, barrier (loads fly under the ~1200cy MFMA window).
template<int EPI>
__global__ __launch_bounds__(512, 2)
void k_gemm256(const u16* __restrict__ A, const u16* __restrict__ Bt,
               const float* __restrict__ bias,
               const float* __restrict__ residf, const u16* __restrict__ residb,
               u16* __restrict__ outb, float* __restrict__ outf,
               const int N, const int K)
{
    __shared__ u16 As[2][8192];
    __shared__ u16 Bs[2][8192];
    const int t  = threadIdx.x;
    const int l  = t & 63;
    const int w  = t >> 6;                       // 0..7
    const int wr = w >> 2, wc = w & 3;           // 2x4 wave grid; wave owns 128x64
    const int m0 = blockIdx.y * 256, n0 = blockIdx.x * 256;
    const int kq = l >> 4, fr = l & 15;

    // staging: thread t fills physical 16B slots t and 512+t of each tile
    int srow0, scol0, srow1, scol1;
    {
        int r0 = t >> 2, s0 = t & 3;
        srow0 = r0; scol0 = (s0 ^ ((r0 >> 1) & 3)) * 8;
        int sl = 512 + t;
        int r1 = sl >> 2, s1 = sl & 3;
        srow1 = r1; scol1 = (s1 ^ ((r1 >> 1) & 3)) * 8;
    }
    const u16* Asrc0 = A  + (size_t)(m0 + srow0) * K + scol0;
    const u16* Asrc1 = A  + (size_t)(m0 + srow1) * K + scol1;
    const u16* Bsrc0 = Bt + (size_t)(n0 + srow0) * K + scol0;
    const u16* Bsrc1 = Bt + (size_t)(n0 + srow1) * K + scol1;
    const int dst0 = w * 512;                    // u16 index (slot w*64), +lane*16B HW
    const int dst1 = 4096 + w * 512;

    // fragment read offsets (u16 units), swizzled to match staging
    int offA[8], offB[4];
    #pragma unroll
    for (int mi = 0; mi < 8; ++mi) {
        int r = wr * 128 + mi * 16 + fr;
        offA[mi] = r * 32 + (kq ^ ((r >> 1) & 3)) * 8;
    }
    #pragma unroll
    for (int ni = 0; ni < 4; ++ni) {
        int r = wc * 64 + ni * 16 + fr;
        offB[ni] = r * 32 + (kq ^ ((r >> 1) & 3)) * 8;
    }

    f32x4 acc[8][4];
    #pragma unroll
    for (int i = 0; i < 8; ++i)
        #pragma unroll
        for (int j = 0; j < 4; ++j) {
            f32x4 z = {0.f, 0.f, 0.f, 0.f};
            acc[i][j] = z;
        }

    const int nt = K >> 5;
    // prologue: stage tile 0
    gload16(Asrc0, &As[0][dst0]); gload16(Asrc1, &As[0][dst1]);
    gload16(Bsrc0, &Bs[0][dst0]); gload16(Bsrc1, &Bs[0][dst1]);
    asm volatile("s_waitcnt vmcnt(0)" ::: "memory");
    __syncthreads();

    for (int tt = 0; tt < nt; ++tt) {
        const int cur = tt & 1;
        if (tt + 1 < nt) {
            const int nxt = cur ^ 1;
            const int ko  = (tt + 1) << 5;
            gload16(Asrc0 + ko, &As[nxt][dst0]); gload16(Asrc1 + ko, &As[nxt][dst1]);
            gload16(Bsrc0 + ko, &Bs[nxt][dst0]); gload16(Bsrc1 + ko, &Bs[nxt][dst1]);
        }
        bf16x8 af[8], bfv[4];
        #pragma unroll
        for (int mi = 0; mi < 8; ++mi) af[mi]  = *(const bf16x8*)&As[cur][offA[mi]];
        #pragma unroll
        for (int ni = 0; ni < 4; ++ni) bfv[ni] = *(const bf16x8*)&Bs[cur][offB[ni]];
        __builtin_amdgcn_s_setprio(1);
        #pragma unroll
        for (int mi = 0; mi < 8; ++mi)
            #pragma unroll
            for (int ni = 0; ni < 4; ++ni)
                acc[mi][ni] = __builtin_amdgcn_mfma_f32_16x16x32_bf16(
                    af[mi], bfv[ni], acc[mi][ni], 0, 0, 0);
        __builtin_amdgcn_s_setprio(0);
        asm volatile("s_waitcnt vmcnt(0)" ::: "memory");
        __syncthreads();
    }

    float bv[4];
    #pragma unroll
    for (int ni = 0; ni < 4; ++ni) bv[ni] = bias[n0 + wc * 64 + ni * 16 + fr];

    #pragma unroll
    for (int mi = 0; mi < 8; ++mi) {
        #pragma unroll
        for (int r = 0; r < 4; ++r) {
            const size_t row  = (size_t)(m0 + wr * 128 + mi * 16 + kq * 4 + r);
            const size_t base = row * N + n0 + wc * 64 + fr;
            #pragma unroll
            for (int ni = 0; ni < 4; ++ni) {
                float v = acc[mi][ni][r] + bv[ni];
                if (EPI == 1) v = gelu_tanh(v);
                if (EPI == 2) v += residf[base + ni * 16];
                if (EPI == 3) { v += bf2f(residb[base + ni * 16]); outf[base + ni * 16] = v; }
                else outb[base + ni * 16] = f2bf(v);
            }
        }
    }
}

// ---------------- windowed attention: 1 wave per (window, head) -------------
__global__ __launch_bounds__(64)
void k_attn(const u16* __restrict__ qkv, const float* __restrict__ btab,
            u16* __restrict__ o, const int tok_base)
{
    __shared__ float Ss[64 * 53];
    const int l    = threadIdx.x;
    const int widl = blockIdx.x >> 4;       // window within chunk (0..255)
    const int head = blockIdx.x & 15;
    const int bl   = widl >> 6;             // batch within chunk (0..3)
    const int g    = widl & 63;
    const int gh   = g >> 3, gw = g & 7;
    const int tok00 = bl * 3136 + gh * 392 + gw * 7;
    const int pl = (l < 49) ? l : 48;
    const int ph = pl / 7, pw = pl - (pl / 7) * 7;
    const int tokl = tok00 + ph * 56 + pw;

    float q[32];
    {
        const size_t qoff = (size_t)tokl * 1536 + head * 32;
        #pragma unroll
        for (int i = 0; i < 4; ++i) {
            u16x8 u = *(const u16x8*)(qkv + qoff + i * 8);
            #pragma unroll
            for (int j = 0; j < 8; ++j) q[i * 8 + j] = bf2f(u[j]);
        }
    }

    float rowmax = -1e30f;
    {
        int j = 0;
        for (int jh = 0; jh < 7; ++jh) {
            for (int jw = 0; jw < 7; ++jw, ++j) {
                const size_t koff = (size_t)(tok00 + jh * 56 + jw) * 1536 + 512 + head * 32;
                float d0 = 0.f, d1 = 0.f, d2 = 0.f, d3 = 0.f;
                #pragma unroll
                for (int i = 0; i < 4; ++i) {
                    u16x8 u = *(const u16x8*)(qkv + koff + i * 8);
                    d0 += q[i * 8 + 0] * bf2f(u[0]); d0 += q[i * 8 + 1] * bf2f(u[1]);
                    d1 += q[i * 8 + 2] * bf2f(u[2]); d1 += q[i * 8 + 3] * bf2f(u[3]);
                    d2 += q[i * 8 + 4] * bf2f(u[4]); d2 += q[i * 8 + 5] * bf2f(u[5]);
                    d3 += q[i * 8 + 6] * bf2f(u[6]); d3 += q[i * 8 + 7] * bf2f(u[7]);
                }
                const float bias = btab[(size_t)((ph - jh + 6) * 13 + (pw - jw + 6)) * 16 + head];
                const float sc = (d0 + d1 + d2 + d3) * 0.04419417382415922f + bias;
                rowmax = fmaxf(rowmax, sc);
                Ss[l * 53 + j] = sc;
            }
        }
    }

    float sum = 0.f;
    for (int j = 0; j < 49; ++j) {
        float p = __expf(Ss[l * 53 + j] - rowmax);
        sum += p;
        Ss[l * 53 + j] = p;
    }

    float oa[32];
    #pragma unroll
    for (int i = 0; i < 32; ++i) oa[i] = 0.f;
    {
        int j = 0;
        for (int jh = 0; jh < 7; ++jh) {
            for (int jw = 0; jw < 7; ++jw, ++j) {
                const size_t voff = (size_t)(tok00 + jh * 56 + jw) * 1536 + 1024 + head * 32;
                const float p = Ss[l * 53 + j];
                #pragma unroll
                for (int i = 0; i < 4; ++i) {
                    u16x8 u = *(const u16x8*)(qkv + voff + i * 8);
                    #pragma unroll
                    for (int jj = 0; jj < 8; ++jj) oa[i * 8 + jj] += p * bf2f(u[jj]);
                }
            }
        }
    }

    if (l < 49) {
        const float inv = 1.0f / sum;
        const size_t obase = (size_t)(tok_base + tokl) * CD + head * 32;
        #pragma unroll
        for (int i = 0; i < 4; ++i) {
            u16x8 u;
            #pragma unroll
            for (int jj = 0; jj < 8; ++jj) u[jj] = f2bf(oa[i * 8 + jj] * inv);
            *(u16x8*)(o + obase + i * 8) = u;
        }
    }
}

// ---------------------------------------------------------------------------
extern "C" void kernel_launch(void* const* d_in, const int* in_sizes, int n_in,
                              void* d_out, int out_size, void* d_ws, size_t ws_size,
                              hipStream_t stream)
{
    (void)in_sizes; (void)n_in; (void)out_size; (void)ws_size;
    const float* x     = (const float*)d_in[0];
    const float* ln1_s = (const float*)d_in[1];
    const float* ln1_b = (const float*)d_in[2];
    const float* w_qkv = (const float*)d_in[3];
    const float* b_qkv = (const float*)d_in[4];
    const float* btab  = (const float*)d_in[5];
    const float* w_mrg = (const float*)d_in[6];
    const float* b_mrg = (const float*)d_in[7];
    const float* ln2_s = (const float*)d_in[8];
    const float* ln2_b = (const float*)d_in[9];
    const float* w1    = (const float*)d_in[10];
    const float* b1    = (const float*)d_in[11];
    const float* w2    = (const float*)d_in[12];
    const float* b2    = (const float*)d_in[13];
    float* out = (float*)d_out;

    // ---- workspace layout (~302 MiB) ----
    u16* wqkvT = (u16*)d_ws;                                // [1536][512]
    u16* wmrgT = wqkvT + (size_t)1536 * 512;                // [512][512]
    u16* w1T   = wmrgT + (size_t)512 * 512;                 // [2048][512]
    u16* w2T   = w1T   + (size_t)2048 * 512;                // [512][2048]
    u16* hbuf  = w2T   + (size_t)512 * 2048;                // [TOKS][512] h, then o
    u16* mbuf  = hbuf  + (size_t)TOKS * 512;                // [TOKS][512] LN2 out
    u16* y1    = mbuf  + (size_t)TOKS * 512;                // [TOKS][512] bf16 residual
    u16* qkvc  = y1    + (size_t)TOKS * 512;                // [12544][1536] chunk
    u16* hidc  = qkvc  + (size_t)12544 * 1536;              // [25088][2048] chunk

    dim3 B256(256), B512(512);

    // weights: transpose + cast to bf16 [N][K]
    k_transpose_cast<<<dim3(48, 16), B256, 0, stream>>>(w_qkv, wqkvT, 512, 1536);
    k_transpose_cast<<<dim3(16, 16), B256, 0, stream>>>(w_mrg, wmrgT, 512, 512);
    k_transpose_cast<<<dim3(64, 16), B256, 0, stream>>>(w1,   w1T,   512, 2048);
    k_transpose_cast<<<dim3(16, 64), B256, 0, stream>>>(w2,   w2T,   2048, 512);

    // LN1: x (f32) -> h (bf16)
    k_layernorm<0><<<dim3(TOKS / 4), B256, 0, stream>>>(x, ln1_s, ln1_b, hbuf);

    // QKV GEMM + attention, chunked over 4 batches (12544 tokens = 49*256 rows)
    for (int c = 0; c < 4; ++c) {
        const size_t tb = (size_t)c * 12544;
        k_gemm256<0><<<dim3(6, 49), B512, 0, stream>>>(
            hbuf + tb * 512, wqkvT, b_qkv, nullptr, nullptr, qkvc, nullptr, 1536, 512);
        k_attn<<<dim3(256 * 16), dim3(64), 0, stream>>>(qkvc, btab, hbuf, (int)tb);
    }

    // merge GEMM + residual(x, f32) -> y1 (bf16)
    k_gemm256<2><<<dim3(2, 196), B512, 0, stream>>>(
        hbuf, wmrgT, b_mrg, x, nullptr, y1, nullptr, 512, 512);

    // LN2: y1 (bf16) -> m (bf16)
    k_layernorm<1><<<dim3(TOKS / 4), B256, 0, stream>>>(y1, ln2_s, ln2_b, mbuf);

    // MLP, chunked over 25088 rows (=98*256)
    for (int c = 0; c < 2; ++c) {
        const size_t rb = (size_t)c * 25088;
        k_gemm256<1><<<dim3(8, 98), B512, 0, stream>>>(
            mbuf + rb * 512, w1T, b1, nullptr, nullptr, hidc, nullptr, 2048, 512);
        k_gemm256<3><<<dim3(2, 98), B512, 0, stream>>>(
            hidc, w2T, b2, nullptr, y1 + rb * 512, nullptr, out + rb * 512, 512, 2048);
    }
}

// Round 4
// 1222.492 us; speedup vs baseline: 1.0203x; 1.0158x over previous
//
#include <hip/hip_runtime.h>
#include <stdint.h>

typedef unsigned short u16;
typedef u16    u16x8  __attribute__((ext_vector_type(8)));
typedef __bf16 bf16x8 __attribute__((ext_vector_type(8)));
typedef float  f32x4  __attribute__((ext_vector_type(4)));

#define TOKS 50176   // B*H*W = 16*56*56
#define CD   512

__device__ __forceinline__ float bf2f(u16 u) {
    union { unsigned int i; float f; } c; c.i = ((unsigned int)u) << 16; return c.f;
}
__device__ __forceinline__ u16 f2bf(float f) {
    union { float f; unsigned int i; } c; c.f = f;
    unsigned int x = c.i;
    return (u16)((x + 0x7fffu + ((x >> 16) & 1u)) >> 16);
}
__device__ __forceinline__ float gelu_tanh(float x) {
    float t = 0.7978845608028654f * (x + 0.044715f * x * x * x);
    float e = __expf(2.0f * t);
    float th = 1.0f - 2.0f / (e + 1.0f);
    return 0.5f * x * (1.0f + th);
}

// global -> LDS direct (16B per lane, wave-uniform LDS base + lane*16)
typedef const __attribute__((address_space(1))) unsigned int gas_u32;
typedef __attribute__((address_space(3))) unsigned int las_u32;
__device__ __forceinline__ void gload16(const u16* g, u16* l) {
    __builtin_amdgcn_global_load_lds((gas_u32*)g, (las_u32*)l, 16, 0, 0);
}

// ---------------- weight transpose + cast: src[K][N] f32 -> dst[N][K] bf16 ----
__global__ __launch_bounds__(256)
void k_transpose_cast(const float* __restrict__ src, u16* __restrict__ dst,
                      const int K, const int N)
{
    __shared__ float tile[32][33];
    const int tx = threadIdx.x & 31, ty = threadIdx.x >> 5;  // ty 0..7
    const int n0 = blockIdx.x * 32, k0 = blockIdx.y * 32;
    #pragma unroll
    for (int i = 0; i < 4; ++i) {
        int r = ty + i * 8;
        tile[r][tx] = src[(size_t)(k0 + r) * N + n0 + tx];
    }
    __syncthreads();
    #pragma unroll
    for (int i = 0; i < 4; ++i) {
        int r = ty + i * 8;
        dst[(size_t)(n0 + r) * K + k0 + tx] = f2bf(tile[tx][r]);
    }
}

// ---------------- LayerNorm over C=512 -> bf16 out --------------------------
// BF=0: f32 input, BF=1: bf16 input
template<int BF>
__global__ __launch_bounds__(256)
void k_layernorm(const void* __restrict__ xin, const float* __restrict__ g,
                 const float* __restrict__ bvec, u16* __restrict__ out)
{
    const int l = threadIdx.x & 63;
    const int w = threadIdx.x >> 6;
    const size_t row = (size_t)blockIdx.x * 4 + w;
    const int c = l * 8;
    float v[8];
    if (BF) {
        u16x8 u = *(const u16x8*)((const u16*)xin + row * CD + c);
        #pragma unroll
        for (int i = 0; i < 8; ++i) v[i] = bf2f(u[i]);
    } else {
        f32x4 a0 = *(const f32x4*)((const float*)xin + row * CD + c);
        f32x4 a1 = *(const f32x4*)((const float*)xin + row * CD + c + 4);
        #pragma unroll
        for (int i = 0; i < 4; ++i) { v[i] = a0[i]; v[4 + i] = a1[i]; }
    }
    float s = 0.f, sq = 0.f;
    #pragma unroll
    for (int i = 0; i < 8; ++i) { s += v[i]; sq += v[i] * v[i]; }
    #pragma unroll
    for (int off = 32; off > 0; off >>= 1) {
        s  += __shfl_xor(s, off);
        sq += __shfl_xor(sq, off);
    }
    const float mean = s * (1.0f / 512.0f);
    const float var  = fmaxf(sq * (1.0f / 512.0f) - mean * mean, 0.0f);
    const float rstd = rsqrtf(var + 1e-6f);
    f32x4 g0 = *(const f32x4*)(g + c),    g1 = *(const f32x4*)(g + c + 4);
    f32x4 b0 = *(const f32x4*)(bvec + c), b1 = *(const f32x4*)(bvec + c + 4);
    u16x8 o;
    #pragma unroll
    for (int i = 0; i < 4; ++i) o[i]     = f2bf((v[i] - mean) * rstd * g0[i] + b0[i]);
    #pragma unroll
    for (int i = 0; i < 4; ++i) o[4 + i] = f2bf((v[4+i] - mean) * rstd * g1[i] + b1[i]);
    *(u16x8*)(out + row * CD + c) = o;
}

// ---------------- bf16 GEMM 256x256, BK=32, ring-3 counted-vmcnt pipeline ---
// C[M][N] = A[M][K] @ Bt[N][K]^T + bias, M%256==0, N%256==0, K%32==0, K/32>=3
// EPI: 0 = bias -> bf16
//      1 = bias + gelu -> bf16
//      2 = bias + f32 resid -> bf16
//      3 = bias + bf16 resid -> f32
// 8 waves (2x4), wave tile 128x64, acc 8x4. LDS: 3-stage ring (96 KB, 1 blk/CU).
// Per iter: s_waitcnt vmcnt(4) [tile t ready, t+1 in flight] -> raw s_barrier
// -> issue tile t+2 -> ds_read tile t -> 32 MFMA. Loads stay in flight across
// barriers (T4); prefetch distance = 2 iterations (~900+ cy) >= load latency.
// LDS slots XOR-swizzled via pre-swizzled global source (linear dest).
// Grid 1-D with bijective XCD remap (m204), n-fast within XCD for A/B L2 reuse.
template<int EPI>
__global__ __launch_bounds__(512, 2)
void k_gemm256(const u16* __restrict__ A, const u16* __restrict__ Bt,
               const float* __restrict__ bias,
               const float* __restrict__ residf, const u16* __restrict__ residb,
               u16* __restrict__ outb, float* __restrict__ outf,
               const int N, const int K, const int nbx)
{
    __shared__ u16 As[3][8192];
    __shared__ u16 Bs[3][8192];
    const int t  = threadIdx.x;
    const int l  = t & 63;
    const int w  = t >> 6;                       // 0..7
    const int wr = w >> 2, wc = w & 3;           // 2x4 wave grid; wave owns 128x64
    // bijective XCD remap: consecutive work per XCD
    const int nwg = gridDim.x;
    const int q = nwg >> 3, r = nwg & 7;
    const int xcd = blockIdx.x & 7, bix = blockIdx.x >> 3;
    const int wg = (xcd < r ? xcd * (q + 1) : r * (q + 1) + (xcd - r) * q) + bix;
    const int m0 = (wg / nbx) * 256, n0 = (wg % nbx) * 256;
    const int kq = l >> 4, fr = l & 15;

    // staging: thread t fills 16B slots t and 512+t of each 16KB tile (linear
    // dest); source column pre-swizzled: col = (slot3 ^ ((row>>1)&3))*8
    const int row0 = t >> 2, q0 = t & 3;
    const int col0 = (q0 ^ ((row0 >> 1) & 3)) * 8;
    const int row1 = 128 + row0;
    const int col1 = (q0 ^ ((row1 >> 1) & 3)) * 8;
    const u16* Asrc0 = A  + (size_t)(m0 + row0) * K + col0;
    const u16* Asrc1 = A  + (size_t)(m0 + row1) * K + col1;
    const u16* Bsrc0 = Bt + (size_t)(n0 + row0) * K + col0;
    const u16* Bsrc1 = Bt + (size_t)(n0 + row1) * K + col1;
    const int dst0 = w * 512;                    // u16 idx; +lane*16B by HW
    const int dst1 = 4096 + w * 512;

    // fragment read offsets (u16 units), swizzle matches staging
    int offA[8], offB[4];
    #pragma unroll
    for (int mi = 0; mi < 8; ++mi) {
        int rr = wr * 128 + mi * 16 + fr;
        offA[mi] = rr * 32 + (kq ^ ((rr >> 1) & 3)) * 8;
    }
    #pragma unroll
    for (int ni = 0; ni < 4; ++ni) {
        int rr = wc * 64 + ni * 16 + fr;
        offB[ni] = rr * 32 + (kq ^ ((rr >> 1) & 3)) * 8;
    }

    f32x4 acc[8][4];
    #pragma unroll
    for (int i = 0; i < 8; ++i)
        #pragma unroll
        for (int j = 0; j < 4; ++j) {
            f32x4 z = {0.f, 0.f, 0.f, 0.f};
            acc[i][j] = z;
        }

    const int nt = K >> 5;
    // prologue: stage tiles 0,1 (8 loads in flight per wave)
    {
        gload16(Asrc0,      &As[0][dst0]); gload16(Asrc1,      &As[0][dst1]);
        gload16(Bsrc0,      &Bs[0][dst0]); gload16(Bsrc1,      &Bs[0][dst1]);
        gload16(Asrc0 + 32, &As[1][dst0]); gload16(Asrc1 + 32, &As[1][dst1]);
        gload16(Bsrc0 + 32, &Bs[1][dst0]); gload16(Bsrc1 + 32, &Bs[1][dst1]);
    }

    int cur = 0;
    for (int tt = 0; tt < nt; ++tt) {
        if (tt == nt - 1) { asm volatile("s_waitcnt vmcnt(0)" ::: "memory"); }
        else              { asm volatile("s_waitcnt vmcnt(4)" ::: "memory"); }
        __builtin_amdgcn_s_barrier();
        __builtin_amdgcn_sched_barrier(0);
        if (tt + 2 < nt) {
            const int pb = (cur == 0) ? 2 : cur - 1;   // (tt+2)%3
            const int ko = (tt + 2) << 5;
            gload16(Asrc0 + ko, &As[pb][dst0]); gload16(Asrc1 + ko, &As[pb][dst1]);
            gload16(Bsrc0 + ko, &Bs[pb][dst0]); gload16(Bsrc1 + ko, &Bs[pb][dst1]);
        }
        bf16x8 af[8], bfv[4];
        #pragma unroll
        for (int mi = 0; mi < 8; ++mi) af[mi]  = *(const bf16x8*)&As[cur][offA[mi]];
        #pragma unroll
        for (int ni = 0; ni < 4; ++ni) bfv[ni] = *(const bf16x8*)&Bs[cur][offB[ni]];
        __builtin_amdgcn_s_setprio(1);
        #pragma unroll
        for (int mi = 0; mi < 8; ++mi)
            #pragma unroll
            for (int ni = 0; ni < 4; ++ni)
                acc[mi][ni] = __builtin_amdgcn_mfma_f32_16x16x32_bf16(
                    af[mi], bfv[ni], acc[mi][ni], 0, 0, 0);
        __builtin_amdgcn_s_setprio(0);
        cur = (cur == 2) ? 0 : cur + 1;
    }

    float bv[4];
    #pragma unroll
    for (int ni = 0; ni < 4; ++ni) bv[ni] = bias[n0 + wc * 64 + ni * 16 + fr];

    #pragma unroll
    for (int mi = 0; mi < 8; ++mi) {
        #pragma unroll
        for (int rr = 0; rr < 4; ++rr) {
            const size_t row  = (size_t)(m0 + wr * 128 + mi * 16 + kq * 4 + rr);
            const size_t base = row * N + n0 + wc * 64 + fr;
            #pragma unroll
            for (int ni = 0; ni < 4; ++ni) {
                float v = acc[mi][ni][rr] + bv[ni];
                if (EPI == 1) v = gelu_tanh(v);
                if (EPI == 2) v += residf[base + ni * 16];
                if (EPI == 3) { v += bf2f(residb[base + ni * 16]); outf[base + ni * 16] = v; }
                else outb[base + ni * 16] = f2bf(v);
            }
        }
    }
}

// ---------------- windowed attention: 1 wave per (window, head) -------------
__global__ __launch_bounds__(64)
void k_attn(const u16* __restrict__ qkv, const float* __restrict__ btab,
            u16* __restrict__ o, const int tok_base)
{
    __shared__ float Ss[64 * 53];
    const int l    = threadIdx.x;
    const int widl = blockIdx.x >> 4;       // window within chunk (0..255)
    const int head = blockIdx.x & 15;
    const int bl   = widl >> 6;             // batch within chunk (0..3)
    const int g    = widl & 63;
    const int gh   = g >> 3, gw = g & 7;
    const int tok00 = bl * 3136 + gh * 392 + gw * 7;
    const int pl = (l < 49) ? l : 48;
    const int ph = pl / 7, pw = pl - (pl / 7) * 7;
    const int tokl = tok00 + ph * 56 + pw;

    float q[32];
    {
        const size_t qoff = (size_t)tokl * 1536 + head * 32;
        #pragma unroll
        for (int i = 0; i < 4; ++i) {
            u16x8 u = *(const u16x8*)(qkv + qoff + i * 8);
            #pragma unroll
            for (int j = 0; j < 8; ++j) q[i * 8 + j] = bf2f(u[j]);
        }
    }

    float rowmax = -1e30f;
    {
        int j = 0;
        for (int jh = 0; jh < 7; ++jh) {
            for (int jw = 0; jw < 7; ++jw, ++j) {
                const size_t koff = (size_t)(tok00 + jh * 56 + jw) * 1536 + 512 + head * 32;
                float d0 = 0.f, d1 = 0.f, d2 = 0.f, d3 = 0.f;
                #pragma unroll
                for (int i = 0; i < 4; ++i) {
                    u16x8 u = *(const u16x8*)(qkv + koff + i * 8);
                    d0 += q[i * 8 + 0] * bf2f(u[0]); d0 += q[i * 8 + 1] * bf2f(u[1]);
                    d1 += q[i * 8 + 2] * bf2f(u[2]); d1 += q[i * 8 + 3] * bf2f(u[3]);
                    d2 += q[i * 8 + 4] * bf2f(u[4]); d2 += q[i * 8 + 5] * bf2f(u[5]);
                    d3 += q[i * 8 + 6] * bf2f(u[6]); d3 += q[i * 8 + 7] * bf2f(u[7]);
                }
                const float bias = btab[(size_t)((ph - jh + 6) * 13 + (pw - jw + 6)) * 16 + head];
                const float sc = (d0 + d1 + d2 + d3) * 0.04419417382415922f + bias;
                rowmax = fmaxf(rowmax, sc);
                Ss[l * 53 + j] = sc;
            }
        }
    }

    float sum = 0.f;
    for (int j = 0; j < 49; ++j) {
        float p = __expf(Ss[l * 53 + j] - rowmax);
        sum += p;
        Ss[l * 53 + j] = p;
    }

    float oa[32];
    #pragma unroll
    for (int i = 0; i < 32; ++i) oa[i] = 0.f;
    {
        int j = 0;
        for (int jh = 0; jh < 7; ++jh) {
            for (int jw = 0; jw < 7; ++jw, ++j) {
                const size_t voff = (size_t)(tok00 + jh * 56 + jw) * 1536 + 1024 + head * 32;
                const float p = Ss[l * 53 + j];
                #pragma unroll
                for (int i = 0; i < 4; ++i) {
                    u16x8 u = *(const u16x8*)(qkv + voff + i * 8);
                    #pragma unroll
                    for (int jj = 0; jj < 8; ++jj) oa[i * 8 + jj] += p * bf2f(u[jj]);
                }
            }
        }
    }

    if (l < 49) {
        const float inv = 1.0f / sum;
        const size_t obase = (size_t)(tok_base + tokl) * CD + head * 32;
        #pragma unroll
        for (int i = 0; i < 4; ++i) {
            u16x8 u;
            #pragma unroll
            for (int jj = 0; jj < 8; ++jj) u[jj] = f2bf(oa[i * 8 + jj] * inv);
            *(u16x8*)(o + obase + i * 8) = u;
        }
    }
}

// ---------------------------------------------------------------------------
extern "C" void kernel_launch(void* const* d_in, const int* in_sizes, int n_in,
                              void* d_out, int out_size, void* d_ws, size_t ws_size,
                              hipStream_t stream)
{
    (void)in_sizes; (void)n_in; (void)out_size; (void)ws_size;
    const float* x     = (const float*)d_in[0];
    const float* ln1_s = (const float*)d_in[1];
    const float* ln1_b = (const float*)d_in[2];
    const float* w_qkv = (const float*)d_in[3];
    const float* b_qkv = (const float*)d_in[4];
    const float* btab  = (const float*)d_in[5];
    const float* w_mrg = (const float*)d_in[6];
    const float* b_mrg = (const float*)d_in[7];
    const float* ln2_s = (const float*)d_in[8];
    const float* ln2_b = (const float*)d_in[9];
    const float* w1    = (const float*)d_in[10];
    const float* b1    = (const float*)d_in[11];
    const float* w2    = (const float*)d_in[12];
    const float* b2    = (const float*)d_in[13];
    float* out = (float*)d_out;

    // ---- workspace layout (~302 MiB) ----
    u16* wqkvT = (u16*)d_ws;                                // [1536][512]
    u16* wmrgT = wqkvT + (size_t)1536 * 512;                // [512][512]
    u16* w1T   = wmrgT + (size_t)512 * 512;                 // [2048][512]
    u16* w2T   = w1T   + (size_t)2048 * 512;                // [512][2048]
    u16* hbuf  = w2T   + (size_t)512 * 2048;                // [TOKS][512] h, then o
    u16* mbuf  = hbuf  + (size_t)TOKS * 512;                // [TOKS][512] LN2 out
    u16* y1    = mbuf  + (size_t)TOKS * 512;                // [TOKS][512] bf16 residual
    u16* qkvc  = y1    + (size_t)TOKS * 512;                // [12544][1536] chunk
    u16* hidc  = qkvc  + (size_t)12544 * 1536;              // [25088][2048] chunk

    dim3 B256(256), B512(512);

    // weights: transpose + cast to bf16 [N][K]
    k_transpose_cast<<<dim3(48, 16), B256, 0, stream>>>(w_qkv, wqkvT, 512, 1536);
    k_transpose_cast<<<dim3(16, 16), B256, 0, stream>>>(w_mrg, wmrgT, 512, 512);
    k_transpose_cast<<<dim3(64, 16), B256, 0, stream>>>(w1,   w1T,   512, 2048);
    k_transpose_cast<<<dim3(16, 64), B256, 0, stream>>>(w2,   w2T,   2048, 512);

    // LN1: x (f32) -> h (bf16)
    k_layernorm<0><<<dim3(TOKS / 4), B256, 0, stream>>>(x, ln1_s, ln1_b, hbuf);

    // QKV GEMM + attention, chunked over 4 batches (12544 tokens = 49*256 rows)
    for (int c = 0; c < 4; ++c) {
        const size_t tb = (size_t)c * 12544;
        k_gemm256<0><<<dim3(49 * 6), B512, 0, stream>>>(
            hbuf + tb * 512, wqkvT, b_qkv, nullptr, nullptr, qkvc, nullptr, 1536, 512, 6);
        k_attn<<<dim3(256 * 16), dim3(64), 0, stream>>>(qkvc, btab, hbuf, (int)tb);
    }

    // merge GEMM + residual(x, f32) -> y1 (bf16)
    k_gemm256<2><<<dim3(196 * 2), B512, 0, stream>>>(
        hbuf, wmrgT, b_mrg, x, nullptr, y1, nullptr, 512, 512, 2);

    // LN2: y1 (bf16) -> m (bf16)
    k_layernorm<1><<<dim3(TOKS / 4), B256, 0, stream>>>(y1, ln2_s, ln2_b, mbuf);

    // MLP, chunked over 25088 rows (=98*256)
    for (int c = 0; c < 2; ++c) {
        const size_t rb = (size_t)c * 25088;
        k_gemm256<1><<<dim3(98 * 8), B512, 0, stream>>>(
            mbuf + rb * 512, w1T, b1, nullptr, nullptr, hidc, nullptr, 2048, 512, 8);
        k_gemm256<3><<<dim3(98 * 2), B512, 0, stream>>>(
            hidc, w2T, b2, nullptr, y1 + rb * 512, nullptr, out + rb * 512, 512, 2048, 2);
    }
}

// Round 5
// 1097.620 us; speedup vs baseline: 1.1363x; 1.1138x over previous
//
#include <hip/hip_runtime.h>
#include <stdint.h>

typedef unsigned short u16;
typedef u16    u16x8  __attribute__((ext_vector_type(8)));
typedef __bf16 bf16x8 __attribute__((ext_vector_type(8)));
typedef float  f32x4  __attribute__((ext_vector_type(4)));

#define TOKS 50176   // B*H*W = 16*56*56
#define CD   512

__device__ __forceinline__ float bf2f(u16 u) {
    union { unsigned int i; float f; } c; c.i = ((unsigned int)u) << 16; return c.f;
}
__device__ __forceinline__ u16 f2bf(float f) {
    union { float f; unsigned int i; } c; c.f = f;
    unsigned int x = c.i;
    return (u16)((x + 0x7fffu + ((x >> 16) & 1u)) >> 16);
}
__device__ __forceinline__ float gelu_tanh(float x) {
    float t = 0.7978845608028654f * (x + 0.044715f * x * x * x);
    float e = __expf(2.0f * t);
    float th = 1.0f - 2.0f / (e + 1.0f);
    return 0.5f * x * (1.0f + th);
}

// global -> LDS direct (16B per lane, wave-uniform LDS base + lane*16)
typedef const __attribute__((address_space(1))) unsigned int gas_u32;
typedef __attribute__((address_space(3))) unsigned int las_u32;
__device__ __forceinline__ void gload16(const u16* g, u16* l) {
    __builtin_amdgcn_global_load_lds((gas_u32*)g, (las_u32*)l, 16, 0, 0);
}

// ---------------- weight transpose + cast: src[K][N] f32 -> dst[N][K] bf16 ----
__global__ __launch_bounds__(256)
void k_transpose_cast(const float* __restrict__ src, u16* __restrict__ dst,
                      const int K, const int N)
{
    __shared__ float tile[32][33];
    const int tx = threadIdx.x & 31, ty = threadIdx.x >> 5;  // ty 0..7
    const int n0 = blockIdx.x * 32, k0 = blockIdx.y * 32;
    #pragma unroll
    for (int i = 0; i < 4; ++i) {
        int r = ty + i * 8;
        tile[r][tx] = src[(size_t)(k0 + r) * N + n0 + tx];
    }
    __syncthreads();
    #pragma unroll
    for (int i = 0; i < 4; ++i) {
        int r = ty + i * 8;
        dst[(size_t)(n0 + r) * K + k0 + tx] = f2bf(tile[tx][r]);
    }
}

// ---------------- LayerNorm over C=512 -> bf16 out --------------------------
// BF=0: f32 input, BF=1: bf16 input
template<int BF>
__global__ __launch_bounds__(256)
void k_layernorm(const void* __restrict__ xin, const float* __restrict__ g,
                 const float* __restrict__ bvec, u16* __restrict__ out)
{
    const int l = threadIdx.x & 63;
    const int w = threadIdx.x >> 6;
    const size_t row = (size_t)blockIdx.x * 4 + w;
    const int c = l * 8;
    float v[8];
    if (BF) {
        u16x8 u = *(const u16x8*)((const u16*)xin + row * CD + c);
        #pragma unroll
        for (int i = 0; i < 8; ++i) v[i] = bf2f(u[i]);
    } else {
        f32x4 a0 = *(const f32x4*)((const float*)xin + row * CD + c);
        f32x4 a1 = *(const f32x4*)((const float*)xin + row * CD + c + 4);
        #pragma unroll
        for (int i = 0; i < 4; ++i) { v[i] = a0[i]; v[4 + i] = a1[i]; }
    }
    float s = 0.f, sq = 0.f;
    #pragma unroll
    for (int i = 0; i < 8; ++i) { s += v[i]; sq += v[i] * v[i]; }
    #pragma unroll
    for (int off = 32; off > 0; off >>= 1) {
        s  += __shfl_xor(s, off);
        sq += __shfl_xor(sq, off);
    }
    const float mean = s * (1.0f / 512.0f);
    const float var  = fmaxf(sq * (1.0f / 512.0f) - mean * mean, 0.0f);
    const float rstd = rsqrtf(var + 1e-6f);
    f32x4 g0 = *(const f32x4*)(g + c),    g1 = *(const f32x4*)(g + c + 4);
    f32x4 b0 = *(const f32x4*)(bvec + c), b1 = *(const f32x4*)(bvec + c + 4);
    u16x8 o;
    #pragma unroll
    for (int i = 0; i < 4; ++i) o[i]     = f2bf((v[i] - mean) * rstd * g0[i] + b0[i]);
    #pragma unroll
    for (int i = 0; i < 4; ++i) o[4 + i] = f2bf((v[4+i] - mean) * rstd * g1[i] + b1[i]);
    *(u16x8*)(out + row * CD + c) = o;
}

// ---------------- bf16 GEMM 128x128, BK=32, ring-3, 3 blocks/CU -------------
// C[M][N] = A[M][K] @ Bt[N][K]^T + bias, M%128==0, N%128==0, K%32==0, K/32>=3
// EPI: 0 = bias -> bf16 ; 1 = bias+gelu -> bf16 ; 2 = bias + f32 resid -> bf16
//      3 = bias + bf16 resid -> f32
// 4 waves (2x2), wave tile 64x64, acc 4x4. LDS ring-3 (48 KB) -> 3 blocks/CU
// co-resident (the m97-style overlap), PLUS counted vmcnt(4) + raw s_barrier
// so tile t+1's loads stay in flight across the barrier (T4). Prefetch
// distance 2 iterations. XCD-bijective 1-D grid remap, n-fast in-XCD.
template<int EPI>
__global__ __launch_bounds__(256)
void k_gemm128(const u16* __restrict__ A, const u16* __restrict__ Bt,
               const float* __restrict__ bias,
               const float* __restrict__ residf, const u16* __restrict__ residb,
               u16* __restrict__ outb, float* __restrict__ outf,
               const int N, const int K, const int nbx)
{
    __shared__ u16 As[3][4096];
    __shared__ u16 Bs[3][4096];
    const int t  = threadIdx.x;
    const int l  = t & 63;
    const int w  = t >> 6;                       // 0..3
    const int wr = w >> 1, wc = w & 1;           // 2x2 wave grid; wave owns 64x64
    // bijective XCD remap (nwg % 8 == 0 for all our grids)
    const int nwg = gridDim.x;
    const int q = nwg >> 3, r = nwg & 7;
    const int xcd = blockIdx.x & 7, bix = blockIdx.x >> 3;
    const int wg = (xcd < r ? xcd * (q + 1) : r * (q + 1) + (xcd - r) * q) + bix;
    const int m0 = (wg / nbx) * 128, n0 = (wg % nbx) * 128;
    const int kq = l >> 4, fr = l & 15;

    // staging: thread t fills 16B slots t and 256+t of each 8KB tile (linear
    // dest); source column pre-swizzled: col = (kslot ^ ((row>>1)&3))*8
    const int row0 = t >> 2, q0 = t & 3;
    const int col0 = (q0 ^ ((row0 >> 1) & 3)) * 8;
    const int row1 = 64 + row0;
    const int col1 = (q0 ^ ((row1 >> 1) & 3)) * 8;
    const u16* Asrc0 = A  + (size_t)(m0 + row0) * K + col0;
    const u16* Asrc1 = A  + (size_t)(m0 + row1) * K + col1;
    const u16* Bsrc0 = Bt + (size_t)(n0 + row0) * K + col0;
    const u16* Bsrc1 = Bt + (size_t)(n0 + row1) * K + col1;
    const int dst0 = w * 512;                    // u16 idx; +lane*16B by HW
    const int dst1 = 2048 + w * 512;

    // fragment read offsets (u16 units), swizzle matches staging
    int offA[4], offB[4];
    #pragma unroll
    for (int mi = 0; mi < 4; ++mi) {
        int rr = wr * 64 + mi * 16 + fr;
        offA[mi] = rr * 32 + (kq ^ ((rr >> 1) & 3)) * 8;
    }
    #pragma unroll
    for (int ni = 0; ni < 4; ++ni) {
        int rr = wc * 64 + ni * 16 + fr;
        offB[ni] = rr * 32 + (kq ^ ((rr >> 1) & 3)) * 8;
    }

    f32x4 acc[4][4];
    #pragma unroll
    for (int i = 0; i < 4; ++i)
        #pragma unroll
        for (int j = 0; j < 4; ++j) {
            f32x4 z = {0.f, 0.f, 0.f, 0.f};
            acc[i][j] = z;
        }

    const int nt = K >> 5;
    // prologue: stage tiles 0,1 (8 loads in flight)
    gload16(Asrc0,      &As[0][dst0]); gload16(Asrc1,      &As[0][dst1]);
    gload16(Bsrc0,      &Bs[0][dst0]); gload16(Bsrc1,      &Bs[0][dst1]);
    gload16(Asrc0 + 32, &As[1][dst0]); gload16(Asrc1 + 32, &As[1][dst1]);
    gload16(Bsrc0 + 32, &Bs[1][dst0]); gload16(Bsrc1 + 32, &Bs[1][dst1]);

    int cur = 0;
    for (int tt = 0; tt < nt; ++tt) {
        if (tt == nt - 1) { asm volatile("s_waitcnt vmcnt(0)" ::: "memory"); }
        else              { asm volatile("s_waitcnt vmcnt(4)" ::: "memory"); }
        __builtin_amdgcn_s_barrier();
        __builtin_amdgcn_sched_barrier(0);
        if (tt + 2 < nt) {
            const int pb = (cur == 0) ? 2 : cur - 1;   // (tt+2)%3
            const int ko = (tt + 2) << 5;
            gload16(Asrc0 + ko, &As[pb][dst0]); gload16(Asrc1 + ko, &As[pb][dst1]);
            gload16(Bsrc0 + ko, &Bs[pb][dst0]); gload16(Bsrc1 + ko, &Bs[pb][dst1]);
        }
        bf16x8 af[4], bfv[4];
        #pragma unroll
        for (int mi = 0; mi < 4; ++mi) af[mi]  = *(const bf16x8*)&As[cur][offA[mi]];
        #pragma unroll
        for (int ni = 0; ni < 4; ++ni) bfv[ni] = *(const bf16x8*)&Bs[cur][offB[ni]];
        __builtin_amdgcn_s_setprio(1);
        #pragma unroll
        for (int mi = 0; mi < 4; ++mi)
            #pragma unroll
            for (int ni = 0; ni < 4; ++ni)
                acc[mi][ni] = __builtin_amdgcn_mfma_f32_16x16x32_bf16(
                    af[mi], bfv[ni], acc[mi][ni], 0, 0, 0);
        __builtin_amdgcn_s_setprio(0);
        cur = (cur == 2) ? 0 : cur + 1;
    }

    float bv[4];
    #pragma unroll
    for (int ni = 0; ni < 4; ++ni) bv[ni] = bias[n0 + wc * 64 + ni * 16 + fr];

    #pragma unroll
    for (int mi = 0; mi < 4; ++mi) {
        #pragma unroll
        for (int rr = 0; rr < 4; ++rr) {
            const size_t row  = (size_t)(m0 + wr * 64 + mi * 16 + kq * 4 + rr);
            const size_t base = row * N + n0 + wc * 64 + fr;
            #pragma unroll
            for (int ni = 0; ni < 4; ++ni) {
                float v = acc[mi][ni][rr] + bv[ni];
                if (EPI == 1) v = gelu_tanh(v);
                if (EPI == 2) v += residf[base + ni * 16];
                if (EPI == 3) { v += bf2f(residb[base + ni * 16]); outf[base + ni * 16] = v; }
                else outb[base + ni * 16] = f2bf(v);
            }
        }
    }
}

// ---------------- windowed attention: 1 wave per (window, head) -------------
__global__ __launch_bounds__(64)
void k_attn(const u16* __restrict__ qkv, const float* __restrict__ btab,
            u16* __restrict__ o, const int tok_base)
{
    __shared__ float Ss[64 * 53];
    const int l    = threadIdx.x;
    const int widl = blockIdx.x >> 4;       // window within chunk (0..255)
    const int head = blockIdx.x & 15;
    const int bl   = widl >> 6;             // batch within chunk (0..3)
    const int g    = widl & 63;
    const int gh   = g >> 3, gw = g & 7;
    const int tok00 = bl * 3136 + gh * 392 + gw * 7;
    const int pl = (l < 49) ? l : 48;
    const int ph = pl / 7, pw = pl - (pl / 7) * 7;
    const int tokl = tok00 + ph * 56 + pw;

    float q[32];
    {
        const size_t qoff = (size_t)tokl * 1536 + head * 32;
        #pragma unroll
        for (int i = 0; i < 4; ++i) {
            u16x8 u = *(const u16x8*)(qkv + qoff + i * 8);
            #pragma unroll
            for (int j = 0; j < 8; ++j) q[i * 8 + j] = bf2f(u[j]);
        }
    }

    float rowmax = -1e30f;
    {
        int j = 0;
        for (int jh = 0; jh < 7; ++jh) {
            for (int jw = 0; jw < 7; ++jw, ++j) {
                const size_t koff = (size_t)(tok00 + jh * 56 + jw) * 1536 + 512 + head * 32;
                float d0 = 0.f, d1 = 0.f, d2 = 0.f, d3 = 0.f;
                #pragma unroll
                for (int i = 0; i < 4; ++i) {
                    u16x8 u = *(const u16x8*)(qkv + koff + i * 8);
                    d0 += q[i * 8 + 0] * bf2f(u[0]); d0 += q[i * 8 + 1] * bf2f(u[1]);
                    d1 += q[i * 8 + 2] * bf2f(u[2]); d1 += q[i * 8 + 3] * bf2f(u[3]);
                    d2 += q[i * 8 + 4] * bf2f(u[4]); d2 += q[i * 8 + 5] * bf2f(u[5]);
                    d3 += q[i * 8 + 6] * bf2f(u[6]); d3 += q[i * 8 + 7] * bf2f(u[7]);
                }
                const float bias = btab[(size_t)((ph - jh + 6) * 13 + (pw - jw + 6)) * 16 + head];
                const float sc = (d0 + d1 + d2 + d3) * 0.04419417382415922f + bias;
                rowmax = fmaxf(rowmax, sc);
                Ss[l * 53 + j] = sc;
            }
        }
    }

    float sum = 0.f;
    for (int j = 0; j < 49; ++j) {
        float p = __expf(Ss[l * 53 + j] - rowmax);
        sum += p;
        Ss[l * 53 + j] = p;
    }

    float oa[32];
    #pragma unroll
    for (int i = 0; i < 32; ++i) oa[i] = 0.f;
    {
        int j = 0;
        for (int jh = 0; jh < 7; ++jh) {
            for (int jw = 0; jw < 7; ++jw, ++j) {
                const size_t voff = (size_t)(tok00 + jh * 56 + jw) * 1536 + 1024 + head * 32;
                const float p = Ss[l * 53 + j];
                #pragma unroll
                for (int i = 0; i < 4; ++i) {
                    u16x8 u = *(const u16x8*)(qkv + voff + i * 8);
                    #pragma unroll
                    for (int jj = 0; jj < 8; ++jj) oa[i * 8 + jj] += p * bf2f(u[jj]);
                }
            }
        }
    }

    if (l < 49) {
        const float inv = 1.0f / sum;
        const size_t obase = (size_t)(tok_base + tokl) * CD + head * 32;
        #pragma unroll
        for (int i = 0; i < 4; ++i) {
            u16x8 u;
            #pragma unroll
            for (int jj = 0; jj < 8; ++jj) u[jj] = f2bf(oa[i * 8 + jj] * inv);
            *(u16x8*)(o + obase + i * 8) = u;
        }
    }
}

// ---------------------------------------------------------------------------
extern "C" void kernel_launch(void* const* d_in, const int* in_sizes, int n_in,
                              void* d_out, int out_size, void* d_ws, size_t ws_size,
                              hipStream_t stream)
{
    (void)in_sizes; (void)n_in; (void)out_size; (void)ws_size;
    const float* x     = (const float*)d_in[0];
    const float* ln1_s = (const float*)d_in[1];
    const float* ln1_b = (const float*)d_in[2];
    const float* w_qkv = (const float*)d_in[3];
    const float* b_qkv = (const float*)d_in[4];
    const float* btab  = (const float*)d_in[5];
    const float* w_mrg = (const float*)d_in[6];
    const float* b_mrg = (const float*)d_in[7];
    const float* ln2_s = (const float*)d_in[8];
    const float* ln2_b = (const float*)d_in[9];
    const float* w1    = (const float*)d_in[10];
    const float* b1    = (const float*)d_in[11];
    const float* w2    = (const float*)d_in[12];
    const float* b2    = (const float*)d_in[13];
    float* out = (float*)d_out;

    // ---- workspace layout (~302 MiB) ----
    u16* wqkvT = (u16*)d_ws;                                // [1536][512]
    u16* wmrgT = wqkvT + (size_t)1536 * 512;                // [512][512]
    u16* w1T   = wmrgT + (size_t)512 * 512;                 // [2048][512]
    u16* w2T   = w1T   + (size_t)2048 * 512;                // [512][2048]
    u16* hbuf  = w2T   + (size_t)512 * 2048;                // [TOKS][512] h, then o
    u16* mbuf  = hbuf  + (size_t)TOKS * 512;                // [TOKS][512] LN2 out
    u16* y1    = mbuf  + (size_t)TOKS * 512;                // [TOKS][512] bf16 residual
    u16* qkvc  = y1    + (size_t)TOKS * 512;                // [12544][1536] chunk
    u16* hidc  = qkvc  + (size_t)12544 * 1536;              // [25088][2048] chunk

    dim3 B256(256);

    // weights: transpose + cast to bf16 [N][K]
    k_transpose_cast<<<dim3(48, 16), B256, 0, stream>>>(w_qkv, wqkvT, 512, 1536);
    k_transpose_cast<<<dim3(16, 16), B256, 0, stream>>>(w_mrg, wmrgT, 512, 512);
    k_transpose_cast<<<dim3(64, 16), B256, 0, stream>>>(w1,   w1T,   512, 2048);
    k_transpose_cast<<<dim3(16, 64), B256, 0, stream>>>(w2,   w2T,   2048, 512);

    // LN1: x (f32) -> h (bf16)
    k_layernorm<0><<<dim3(TOKS / 4), B256, 0, stream>>>(x, ln1_s, ln1_b, hbuf);

    // QKV GEMM + attention, chunked over 4 batches (12544 tokens = 98*128 rows)
    for (int c = 0; c < 4; ++c) {
        const size_t tb = (size_t)c * 12544;
        k_gemm128<0><<<dim3(98 * 12), B256, 0, stream>>>(
            hbuf + tb * 512, wqkvT, b_qkv, nullptr, nullptr, qkvc, nullptr, 1536, 512, 12);
        k_attn<<<dim3(256 * 16), dim3(64), 0, stream>>>(qkvc, btab, hbuf, (int)tb);
    }

    // merge GEMM + residual(x, f32) -> y1 (bf16)
    k_gemm128<2><<<dim3(392 * 4), B256, 0, stream>>>(
        hbuf, wmrgT, b_mrg, x, nullptr, y1, nullptr, 512, 512, 4);

    // LN2: y1 (bf16) -> m (bf16)
    k_layernorm<1><<<dim3(TOKS / 4), B256, 0, stream>>>(y1, ln2_s, ln2_b, mbuf);

    // MLP, chunked over 25088 rows (=196*128)
    for (int c = 0; c < 2; ++c) {
        const size_t rb = (size_t)c * 25088;
        k_gemm128<1><<<dim3(196 * 16), B256, 0, stream>>>(
            mbuf + rb * 512, w1T, b1, nullptr, nullptr, hidc, nullptr, 2048, 512, 16);
        k_gemm128<3><<<dim3(196 * 4), B256, 0, stream>>>(
            hidc, w2T, b2, nullptr, y1 + rb * 512, nullptr, out + rb * 512, 512, 2048, 4);
    }
}